// Round 11
// baseline (892.754 us; speedup 1.0000x reference)
//
#include <hip/hip_runtime.h>

#define TT 512   // sequence length
#define BB 64    // batch
#define HH 128   // hidden
#define G4 512   // 4*H
#define PF 8     // prefetch ring depth (even, divides TT)

typedef short bf16x8 __attribute__((ext_vector_type(8)));
typedef short s16x4  __attribute__((ext_vector_type(4)));
typedef float f32x4  __attribute__((ext_vector_type(4)));
typedef _Float16 h2f __attribute__((ext_vector_type(2)));
typedef _Float16 h8f __attribute__((ext_vector_type(8)));

__device__ __forceinline__ unsigned short f2bf(float x) {
    unsigned u = __float_as_uint(x);
    u += 0x7fff + ((u >> 16) & 1);           // RNE
    return (unsigned short)(u >> 16);
}
__device__ __forceinline__ float bf2f(unsigned short h) {
    return __uint_as_float(((unsigned)h) << 16);
}
__device__ __forceinline__ float fdot2_(h2f a, h2f b, float c) {
#if __has_builtin(__builtin_amdgcn_fdot2)
    return __builtin_amdgcn_fdot2(a, b, c, false);
#else
    return c + (float)a[0] * (float)b[0] + (float)a[1] * (float)b[1];
#endif
}

// ---------------- fp32 -> bf16 hi/lo split (memory-bound) ----------------
__global__ __launch_bounds__(256) void convert_hilo(
    const float4* __restrict__ src, s16x4* __restrict__ hi,
    s16x4* __restrict__ lo, int n4)
{
    for (int i = blockIdx.x * 256 + threadIdx.x; i < n4; i += gridDim.x * 256) {
        float4 f = src[i];
        float fa[4] = {f.x, f.y, f.z, f.w};
        s16x4 h, l;
        #pragma unroll
        for (int e = 0; e < 4; ++e) {
            unsigned short hh = f2bf(fa[e]);
            h[e] = (short)hh;
            l[e] = (short)f2bf(fa[e] - bf2f(hh));
        }
        hi[i] = h;
        lo[i] = l;
    }
}

// ---------------- MFMA pre-GEMM v2 (proven R6/R7): A pre-split, W in-kernel ----
template<int K>
__global__ __launch_bounds__(256) void gemm_mfma2(
    const short* __restrict__ Ahi, const short* __restrict__ Alo,
    const float* __restrict__ W,
    const float* __restrict__ b0, const float* __restrict__ b1,
    float* __restrict__ C)
{
    constexpr int NC  = K / 32;
    constexpr int LDA = 40;                  // shorts per staged row (32 + 8 pad)
    __shared__ short Ahi_s[128 * LDA], Alo_s[128 * LDA];
    __shared__ short Whi_s[128 * LDA], Wlo_s[128 * LDA];

    const int bm  = blockIdx.x * 128;
    const int bn  = blockIdx.y * 128;
    const int tid = threadIdx.x;
    const int wv  = tid >> 6;
    const int l   = tid & 63;
    const int jl  = l & 15;
    const int rg  = l >> 4;
    const int wr  = wv >> 1;
    const int wc  = wv & 1;

    const int sr = tid >> 1;
    const int sc = (tid & 1) * 16;

    const short* Aph = Ahi + (size_t)(bm + sr) * K + sc;
    const short* Apl = Alo + (size_t)(bm + sr) * K + sc;
    const float* Wp  = W   + (size_t)(bn + sr) * K + sc;

    f32x4 acc[4][4];
    #pragma unroll
    for (int i = 0; i < 4; ++i)
        #pragma unroll
        for (int j = 0; j < 4; ++j)
            acc[i][j] = (f32x4){0.f, 0.f, 0.f, 0.f};

    bf16x8 pah[2], pal[2];
    float4 pw[4];
    pah[0] = *(const bf16x8*)(Aph);
    pah[1] = *(const bf16x8*)(Aph + 8);
    pal[0] = *(const bf16x8*)(Apl);
    pal[1] = *(const bf16x8*)(Apl + 8);
    #pragma unroll
    for (int q = 0; q < 4; ++q) pw[q] = *(const float4*)(Wp + q * 4);

    #pragma unroll 1
    for (int c = 0; c < NC; ++c) {
        __syncthreads();
        {
            int off = sr * LDA + sc;
            *(bf16x8*)&Ahi_s[off]     = pah[0];
            *(bf16x8*)&Ahi_s[off + 8] = pah[1];
            *(bf16x8*)&Alo_s[off]     = pal[0];
            *(bf16x8*)&Alo_s[off + 8] = pal[1];
            #pragma unroll
            for (int q = 0; q < 4; ++q) {
                float fw[4] = {pw[q].x, pw[q].y, pw[q].z, pw[q].w};
                s16x4 h, lo4;
                #pragma unroll
                for (int e = 0; e < 4; ++e) {
                    unsigned short hh = f2bf(fw[e]);
                    h[e]   = (short)hh;
                    lo4[e] = (short)f2bf(fw[e] - bf2f(hh));
                }
                *(s16x4*)&Whi_s[off + q * 4] = h;
                *(s16x4*)&Wlo_s[off + q * 4] = lo4;
            }
        }
        __syncthreads();
        if (c + 1 < NC) {
            pah[0] = *(const bf16x8*)(Aph + (c + 1) * 32);
            pah[1] = *(const bf16x8*)(Aph + (c + 1) * 32 + 8);
            pal[0] = *(const bf16x8*)(Apl + (c + 1) * 32);
            pal[1] = *(const bf16x8*)(Apl + (c + 1) * 32 + 8);
            #pragma unroll
            for (int q = 0; q < 4; ++q)
                pw[q] = *(const float4*)(Wp + (c + 1) * 32 + q * 4);
        }
        bf16x8 ah[4], al[4], wh[4], wl[4];
        #pragma unroll
        for (int t = 0; t < 4; ++t) {
            int ra = (wr * 64 + t * 16 + jl) * LDA + rg * 8;
            ah[t] = *(const bf16x8*)&Ahi_s[ra];
            al[t] = *(const bf16x8*)&Alo_s[ra];
            int rw = (wc * 64 + t * 16 + jl) * LDA + rg * 8;
            wh[t] = *(const bf16x8*)&Whi_s[rw];
            wl[t] = *(const bf16x8*)&Wlo_s[rw];
        }
        #pragma unroll
        for (int tm = 0; tm < 4; ++tm)
            #pragma unroll
            for (int tn = 0; tn < 4; ++tn) {
                acc[tm][tn] = __builtin_amdgcn_mfma_f32_16x16x32_bf16(ah[tm], wh[tn], acc[tm][tn], 0, 0, 0);
                acc[tm][tn] = __builtin_amdgcn_mfma_f32_16x16x32_bf16(ah[tm], wl[tn], acc[tm][tn], 0, 0, 0);
                acc[tm][tn] = __builtin_amdgcn_mfma_f32_16x16x32_bf16(al[tm], wh[tn], acc[tm][tn], 0, 0, 0);
            }
    }

    // epilogue: C layout col=lane&15 (n), row=(lane>>4)*4+r (m)
    #pragma unroll
    for (int tn = 0; tn < 4; ++tn) {
        int n = bn + wc * 64 + tn * 16 + jl;
        float bias = b0[n] + b1[n];
        #pragma unroll
        for (int tm = 0; tm < 4; ++tm) {
            int m = bm + wr * 64 + tm * 16 + rg * 4;
            #pragma unroll
            for (int r = 0; r < 4; ++r)
                C[(size_t)(m + r) * G4 + n] = acc[tm][tn][r] + bias;
        }
    }
}

// ---------------- LSTM scan v8d: 16 waves, k-split, DPP exchange ----------------
// 128 blocks = 2dir x 64batch, 1024 thr (16 waves -> 4 waves/SIMD).
// Lane l: q = l&3 (gate), kh = (l>>2)&1 (k-half), ci = l>>3 (cell 0..7).
// Cell j = w*8 + ci; row = q*HH + j. Lane dots row over k in [kh*64, kh*64+64).
// Partner partial (lane^4) via DPP row-shift; direction PROVEN by R9/R10
// bit-equivalence (DPP select == xor-swizzle): kh0 takes row_shl:4 (in[l+4]),
// kh1 takes row_shr:4 (in[l-4]).
// R8-R10 BUG (fixed here): pf[u] must be read into pv BEFORE the ring refill
// overwrites it -- gate must use pre[s], not pre[s+PF].
// Both kh copies compute c identically; kh0 writes h_lds, kh1 writes out.
__global__ __launch_bounds__(1024) void lstm_scan_v8d(
    const float* __restrict__ pre_f, const float* __restrict__ pre_b,
    const float* __restrict__ whh_f, const float* __restrict__ whh_b,
    float* __restrict__ out)
{
    const int dir = blockIdx.x >> 6;
    const int b   = blockIdx.x & 63;
    const float* __restrict__ pre  = dir ? pre_b : pre_f;
    const float* __restrict__ w_hh = dir ? whh_b : whh_f;

    const int tid = threadIdx.x;
    const int w   = tid >> 6;        // wave 0..15
    const int l   = tid & 63;
    const int q   = l & 3;           // gate type (i,f,g,o)
    const int kh  = (l >> 2) & 1;    // k-half
    const int ci  = l >> 3;          // cell-in-wave 0..7
    const int j   = w * 8 + ci;      // cell 0..127
    const int row = q * HH + j;      // gate row 0..511

    __shared__ _Float16 h_lds[2][HH];

    // weights: row over this lane's k-half, packed fp16 (32 dwords)
    h2f wv[32];
    #pragma unroll
    for (int k = 0; k < 64; k += 4) {
        float4 f = *(const float4*)&w_hh[(size_t)row * HH + kh * 64 + k];
        wv[k / 2]     = (h2f){(_Float16)f.x, (_Float16)f.y};
        wv[k / 2 + 1] = (h2f){(_Float16)f.z, (_Float16)f.w};
    }

    if (tid < 2 * HH) ((_Float16*)h_lds)[tid] = (_Float16)0.f;

    const size_t base = (size_t)b * TT * G4 + row;
    float pf[PF];
    #pragma unroll
    for (int u = 0; u < PF; ++u) {
        int tau = dir ? (TT - 1 - u) : u;
        pf[u] = pre[base + (size_t)tau * G4];
    }

    float c = 0.f;
    const float ASIG = -1.4426950408889634f;  // -log2(e)
    const float ATAN =  2.8853900817779268f;  // 2*log2(e)
    const float aa = (q == 2) ? ATAN : ASIG;

    __syncthreads();

    for (int s0 = 0; s0 < TT; s0 += PF) {
        #pragma unroll
        for (int u = 0; u < PF; ++u) {
            const int s = s0 + u;
            const int cur = u & 1;            // parity(s) == parity(u)

            // partial dot over own k-half (8 broadcast b128 reads, 2 addrs/wave)
            const _Float16* hb = &h_lds[cur][kh * 64];
            float a0 = 0.f, a1 = 0.f, a2 = 0.f, a3 = 0.f;
            #pragma unroll
            for (int k8 = 0; k8 < 8; ++k8) {
                union { h8f v; h2f p[4]; } hu;
                hu.v = *(const h8f*)&hb[k8 * 8];
                a0 = fdot2_(wv[k8 * 4 + 0], hu.p[0], a0);
                a1 = fdot2_(wv[k8 * 4 + 1], hu.p[1], a1);
                a2 = fdot2_(wv[k8 * 4 + 2], hu.p[2], a2);
                a3 = fdot2_(wv[k8 * 4 + 3], hu.p[3], a3);
            }
            float P = (a0 + a1) + (a2 + a3);

            // exchange partner's k-half partial (lane^4), pure VALU.
            // row_shr:4 -> out[i]=in[i-4]; row_shl:4 -> out[i]=in[i+4].
            int Pi = __float_as_int(P);
            float pshr = __int_as_float(__builtin_amdgcn_update_dpp(Pi, Pi, 0x114, 0xF, 0xF, false));
            float pshl = __int_as_float(__builtin_amdgcn_update_dpp(Pi, Pi, 0x104, 0xF, 0xF, false));
            float recv = kh ? pshr : pshl;

            // read THIS step's pre BEFORE the refill clobbers pf[u]  (R8-R10 bug)
            float pv = pf[u];

            // ring refill (clamped, branch-free)
            {
                int sn = s + PF;
                int taun = dir ? (TT - 1 - sn) : sn;
                taun = taun < 0 ? 0 : (taun > TT - 1 ? TT - 1 : taun);
                pf[u] = pre[base + (size_t)taun * G4];
            }

            float gate = pv + P + recv;

            // own-gate activation: sigmoid (i,f,o) / tanh (g)
            float e = __builtin_amdgcn_exp2f(aa * gate);
            float r = __builtin_amdgcn_rcpf(1.f + e);
            float v = (q == 2) ? (1.f - 2.f * r) : r;

            // quad rotations (proven v6): at q==0 lanes, sf=f-sig, tg=g-tanh, so=o-sig
            int vi = __float_as_int(v);
            float sf = __int_as_float(__builtin_amdgcn_update_dpp(vi, vi, 0x39, 0xF, 0xF, false));
            float tg = __int_as_float(__builtin_amdgcn_update_dpp(vi, vi, 0x4E, 0xF, 0xF, false));
            float so = __int_as_float(__builtin_amdgcn_update_dpp(vi, vi, 0x93, 0xF, 0xF, false));

            if (q == 0) {
                c = fmaf(sf, c, v * tg);                  // identical on both kh copies
                float e2 = __builtin_amdgcn_exp2f(ATAN * c);
                float r2 = __builtin_amdgcn_rcpf(1.f + e2);
                float h  = so * (1.f - 2.f * r2);
                if (kh == 0) {
                    h_lds[cur ^ 1][j] = (_Float16)h;      // tail split: LDS write
                } else {
                    int tau = dir ? (TT - 1 - s) : s;     // tail split: global write
                    out[((size_t)b * TT + tau) * (2 * HH) + dir * HH + j] = h;
                }
            }
            __syncthreads();
        }
    }
}

// ---------------- FC v2 (proven R7) ----------------
__global__ __launch_bounds__(256) void fc_v2(
    const float* __restrict__ h2, const float* __restrict__ w_fc,
    const float* __restrict__ b_fc, float* __restrict__ out)
{
    __shared__ float4 wsT[64][64];          // [k4][n]
    const int tid = threadIdx.x;
    const int bm  = blockIdx.x * 64;
    const int n   = tid & 63;
    const int mg  = tid >> 6;

    #pragma unroll
    for (int qq = 0; qq < 16; ++qq) {
        int id = qq * 256 + tid;
        int nn = id >> 6, k4 = id & 63;
        wsT[k4][nn] = *(const float4*)&w_fc[(size_t)nn * 256 + k4 * 4];
    }
    __syncthreads();

    const float bias = b_fc[n];
    const float* hrow = h2 + (size_t)(bm + mg * 16) * 256;

    float acc[16];
    #pragma unroll
    for (int mi = 0; mi < 16; ++mi) acc[mi] = 0.f;

    #pragma unroll 2
    for (int k4 = 0; k4 < 64; ++k4) {
        float4 w4 = wsT[k4][n];
        #pragma unroll
        for (int mi = 0; mi < 16; ++mi) {
            float4 h4 = *(const float4*)(hrow + (size_t)mi * 256 + k4 * 4);
            acc[mi] = fmaf(h4.x, w4.x, acc[mi]);
            acc[mi] = fmaf(h4.y, w4.y, acc[mi]);
            acc[mi] = fmaf(h4.z, w4.z, acc[mi]);
            acc[mi] = fmaf(h4.w, w4.w, acc[mi]);
        }
    }
    #pragma unroll
    for (int mi = 0; mi < 16; ++mi)
        out[(size_t)(bm + mg * 16 + mi) * 64 + n] = acc[mi] + bias;
}

extern "C" void kernel_launch(void* const* d_in, const int* in_sizes, int n_in,
                              void* d_out, int out_size, void* d_ws, size_t ws_size,
                              hipStream_t stream) {
    const float* x        = (const float*)d_in[0];
    const float* w_ih_l0  = (const float*)d_in[1];
    const float* w_hh_l0  = (const float*)d_in[2];
    const float* b_ih_l0  = (const float*)d_in[3];
    const float* b_hh_l0  = (const float*)d_in[4];
    const float* w_ih_l0r = (const float*)d_in[5];
    const float* w_hh_l0r = (const float*)d_in[6];
    const float* b_ih_l0r = (const float*)d_in[7];
    const float* b_hh_l0r = (const float*)d_in[8];
    const float* w_ih_l1  = (const float*)d_in[9];
    const float* w_hh_l1  = (const float*)d_in[10];
    const float* b_ih_l1  = (const float*)d_in[11];
    const float* b_hh_l1  = (const float*)d_in[12];
    const float* w_ih_l1r = (const float*)d_in[13];
    const float* w_hh_l1r = (const float*)d_in[14];
    const float* b_ih_l1r = (const float*)d_in[15];
    const float* b_hh_l1r = (const float*)d_in[16];
    const float* w_fc     = (const float*)d_in[17];
    const float* b_fc     = (const float*)d_in[18];

    float* ws    = (float*)d_ws;
    float* pre_f = ws;                       // 16,777,216 floats
    float* pre_b = ws + 16777216;            // 16,777,216 floats
    float* out0  = ws + 2 * 16777216;        // 8,388,608 floats
    float* out1  = out0 + 8388608;           // 8,388,608 floats

    // A hi/lo aliases (lifetimes proven R6/R7):
    short* xhi  = (short*)out0;
    short* xlo  = xhi + 2097152;
    short* a1hi = (short*)out1;
    short* a1lo = a1hi + 8388608;

    dim3 gg(256, 4);  // M/128 x 512/128

    // Layer 0
    convert_hilo<<<2048, 256, 0, stream>>>((const float4*)x, (s16x4*)xhi, (s16x4*)xlo, 524288);
    gemm_mfma2<64><<<gg, 256, 0, stream>>>(xhi, xlo, w_ih_l0,  b_ih_l0,  b_hh_l0,  pre_f);
    gemm_mfma2<64><<<gg, 256, 0, stream>>>(xhi, xlo, w_ih_l0r, b_ih_l0r, b_hh_l0r, pre_b);
    lstm_scan_v8d<<<128, 1024, 0, stream>>>(pre_f, pre_b, w_hh_l0, w_hh_l0r, out0);

    // Layer 1
    convert_hilo<<<2048, 256, 0, stream>>>((const float4*)out0, (s16x4*)a1hi, (s16x4*)a1lo, 2097152);
    gemm_mfma2<256><<<gg, 256, 0, stream>>>(a1hi, a1lo, w_ih_l1,  b_ih_l1,  b_hh_l1,  pre_f);
    gemm_mfma2<256><<<gg, 256, 0, stream>>>(a1hi, a1lo, w_ih_l1r, b_ih_l1r, b_hh_l1r, pre_b);
    lstm_scan_v8d<<<128, 1024, 0, stream>>>(pre_f, pre_b, w_hh_l1, w_hh_l1r, out1);

    // FC
    fc_v2<<<512, 256, 0, stream>>>(out1, w_fc, b_fc, (float*)d_out);
}